// Round 2
// baseline (693.975 us; speedup 1.0000x reference)
//
#include <hip/hip_runtime.h>
#include <math.h>

// factor [65536, 2048] fp32 -> scalar:
//   f = row-L2-normalize(factor); adj[i] = <f_i, f_{i+1}>;
//   out = -0.01 * 2 * mean(adj)
//
// Pass 1 (HBM-bound, ~90 us floor): per-wave chunk of 16 rows, register
// rotation A/B/C so the next row's loads are in flight while the current
// pair reduces. Writes per-row sumsq and per-pair dot (fp32).
// Pass 2 (tiny): one 1024-thread block, fp32 normalize, fp64 accumulate,
// plain store (no atomic, no memset dispatch).

#define N_ROWS 65536
#define N_COLS 2048
#define RPW 16   // rows per wave; 1/16 boundary re-read; 4096 waves = 16/CU

__device__ __forceinline__ void load_row(float4 dst[8], const float4* __restrict__ rowp,
                                         int r, int lane) {
    const float4* p = rowp + ((long)r << 9) + lane;   // 512 float4 per row
    #pragma unroll
    for (int k = 0; k < 8; ++k) dst[k] = p[(long)k * 64];
}

__device__ __forceinline__ float row_sq(const float4 a[8]) {
    float s = 0.f;
    #pragma unroll
    for (int k = 0; k < 8; ++k)
        s = fmaf(a[k].x, a[k].x, fmaf(a[k].y, a[k].y,
            fmaf(a[k].z, a[k].z, fmaf(a[k].w, a[k].w, s))));
    return s;
}

__device__ __forceinline__ float row_dot(const float4 a[8], const float4 b[8]) {
    float s = 0.f;
    #pragma unroll
    for (int k = 0; k < 8; ++k)
        s = fmaf(a[k].x, b[k].x, fmaf(a[k].y, b[k].y,
            fmaf(a[k].z, b[k].z, fmaf(a[k].w, b[k].w, s))));
    return s;
}

__global__ __launch_bounds__(256) void tcr_pass1(const float* __restrict__ x,
                                                 float* __restrict__ sq,
                                                 float* __restrict__ cross) {
    const int wid  = (blockIdx.x * 256 + threadIdx.x) >> 6;   // global wave id
    const int lane = threadIdx.x & 63;
    const int r0   = wid * RPW;
    const float4* rowp = (const float4*)x;

    float4 A[8], B[8];
    load_row(A, rowp, r0, lane);
    load_row(B, rowp, r0 + 1, lane);      // prefetch row r0+1 before reducing r0

    float s0 = row_sq(A);
    #pragma unroll
    for (int off = 32; off; off >>= 1) s0 += __shfl_xor(s0, off, 64);
    if (lane == 0) sq[r0] = s0;

    #pragma unroll
    for (int i = 1; i <= RPW; ++i) {
        // A = row r0+i-1, B = row r0+i. Prefetch row r0+i+1 first.
        float4 C[8];
        if (i < RPW) {
            int rn = r0 + i + 1;
            if (rn > N_ROWS - 1) rn = N_ROWS - 1;   // last chunk: clamp (harmless)
            load_row(C, rowp, rn, lane);
        }
        float sb = row_sq(B);
        float cr = row_dot(A, B);
        #pragma unroll
        for (int off = 32; off; off >>= 1) {
            sb += __shfl_xor(sb, off, 64);
            cr += __shfl_xor(cr, off, 64);
        }
        if (lane == 0) {
            cross[r0 + i - 1] = cr;          // pair (r0+i-1, r0+i); last wave's
                                             // cross[65535] is garbage but unread
            if (i < RPW) sq[r0 + i] = sb;    // row r0+i owned by this chunk
        }
        if (i < RPW) {
            #pragma unroll
            for (int k = 0; k < 8; ++k) { A[k] = B[k]; B[k] = C[k]; }
        }
    }
}

__global__ __launch_bounds__(1024) void tcr_pass2(const float* __restrict__ sq,
                                                  const float* __restrict__ cross,
                                                  float* __restrict__ out) {
    const int tid = threadIdx.x;
    double acc = 0.0;
    for (int i = tid; i < N_ROWS - 1; i += 1024) {
        float ni = fmaxf(sqrtf(sq[i]),     1e-12f);
        float nj = fmaxf(sqrtf(sq[i + 1]), 1e-12f);
        acc += (double)(cross[i] / (ni * nj));
    }
    // wave-level fp64 butterfly, then 16-wave LDS combine
    #pragma unroll
    for (int off = 32; off; off >>= 1) acc += __shfl_xor(acc, off, 64);
    __shared__ double sd[16];
    if ((tid & 63) == 0) sd[tid >> 6] = acc;
    __syncthreads();
    if (tid == 0) {
        double t = 0.0;
        #pragma unroll
        for (int w = 0; w < 16; ++w) t += sd[w];
        out[0] = (float)(t * (-2.0 * 0.01 / (double)(N_ROWS - 1)));
    }
}

extern "C" void kernel_launch(void* const* d_in, const int* in_sizes, int n_in,
                              void* d_out, int out_size, void* d_ws, size_t ws_size,
                              hipStream_t stream) {
    const float* factor = (const float*)d_in[0];
    float* out = (float*)d_out;

    float* sq    = (float*)d_ws;        // [N_ROWS]
    float* cross = sq + N_ROWS;         // [N_ROWS] (last slot scratch/unused)

    const int n_waves  = N_ROWS / RPW;  // 4096
    const int n_blocks = n_waves / 4;   // 1024 blocks x 4 waves
    tcr_pass1<<<n_blocks, 256, 0, stream>>>(factor, sq, cross);
    tcr_pass2<<<1, 1024, 0, stream>>>(sq, cross, out);
}